// Round 11
// baseline (277.971 us; speedup 1.0000x reference)
//
#include <hip/hip_runtime.h>

// Cumulative product along last dim of (4096, 32768) fp32.
// SINGLE-PASS DECOUPLED-LOOKBACK SCAN (rocPRIM/CUB structure):
//   row -> 16 tiles x 2048 elems, ONE WAVE PER TILE (65536 waves, ~20/CU).
//   Per wave: 8 independent nt loads (burst) -> pair-ILP DPP scan ->
//   publish tile aggregate -> lookback over predecessors -> scale -> 8-store burst.
// Value-as-flag: aggregates/prefixes are strictly positive (inputs in
// [0.95,1.05]) so 0.0 == unpublished; relaxed agent-scope atomics, no fences.
// Block-level ticket makes processing order = scheduling order (no deadlock).
// Flags in d_ws, zeroed via hipMemsetAsync inside every launch (replay-safe).

#define COLS   32768
#define CHUNK  256                 // 64 lanes x float4
#define TCH    8                   // chunks per tile
#define TILE   (TCH * CHUNK)       // 2048 elems
#define SEGS   (COLS / TILE)       // 16 tiles per row
#define TPB    256
#define WPB    (TPB / 64)          // 4 waves (tiles) per block

typedef float f32x4 __attribute__((ext_vector_type(4)));

#define ONE_BITS 0x3f800000        // 1.0f bits (multiplicative identity)

template <int CTRL, int RM, int BM>
__device__ __forceinline__ float mul_dpp(float x) {
    int s = __builtin_amdgcn_update_dpp(ONE_BITS, __float_as_int(x),
                                        CTRL, RM, BM, false);
    return x * __int_as_float(s);
}

__device__ __forceinline__ float wave_scan(float t) {
    t = mul_dpp<0x111, 0xf, 0xf>(t);   // row_shr:1
    t = mul_dpp<0x112, 0xf, 0xf>(t);   // row_shr:2
    t = mul_dpp<0x114, 0xf, 0xf>(t);   // row_shr:4
    t = mul_dpp<0x118, 0xf, 0xf>(t);   // row_shr:8
    t = mul_dpp<0x142, 0xa, 0xf>(t);   // row_bcast:15 -> rows 1,3
    t = mul_dpp<0x143, 0xc, 0xf>(t);   // row_bcast:31 -> rows 2,3
    return t;
}

__device__ __forceinline__ float excl(float t) {
    return __int_as_float(__builtin_amdgcn_update_dpp(
        ONE_BITS, __float_as_int(t), 0x138, 0xf, 0xf, false));
}

__device__ __forceinline__ float read63(float t) {
    return __int_as_float(__builtin_amdgcn_readlane(__float_as_int(t), 63));
}

__global__ __launch_bounds__(TPB) void cumprod_lookback(
    const float* __restrict__ x, float* __restrict__ out,
    unsigned* __restrict__ ticket_ctr,
    float* __restrict__ agg, float* __restrict__ pref) {

    __shared__ unsigned tk_s;
    if (threadIdx.x == 0) tk_s = atomicAdd(ticket_ctr, 1u);
    __syncthreads();

    const int lane = threadIdx.x & 63;
    const int wid  = threadIdx.x >> 6;
    const unsigned tile = tk_s * WPB + wid;
    const int row = tile >> 4;               // SEGS = 16
    const int seg = tile & (SEGS - 1);

    const size_t base = (size_t)row * COLS + (size_t)seg * TILE + (size_t)lane * 4;
    const float* px = x + base;
    float*       po = out + base;

    // ---- burst-load the whole tile: 8 independent nt loads ----
    f32x4 buf[TCH];
    #pragma unroll
    for (int j = 0; j < TCH; ++j)
        buf[j] = __builtin_nontemporal_load(
            reinterpret_cast<const f32x4*>(px + j * CHUNK));

    // ---- local scan: 4 chunk-pairs, independent DPP chains per pair ----
    float carry = 1.0f;
    #pragma unroll
    for (int pq = 0; pq < TCH / 2; ++pq) {
        f32x4 vA = buf[2 * pq], vB = buf[2 * pq + 1];
        vA[1] *= vA[0]; vB[1] *= vB[0];
        vA[2] *= vA[1]; vB[2] *= vB[1];
        vA[3] *= vA[2]; vB[3] *= vB[2];
        float tA = wave_scan(vA[3]);
        float tB = wave_scan(vB[3]);
        float exA = excl(tA), exB = excl(tB);
        float TA = read63(tA), TB = read63(tB);
        const float mA = carry * exA;
        const float cA = carry * TA;
        const float mB = cA * exB;
        carry = cA * TB;
        vA[0] *= mA; vA[1] *= mA; vA[2] *= mA; vA[3] *= mA;
        vB[0] *= mB; vB[1] *= mB; vB[2] *= mB; vB[3] *= mB;
        buf[2 * pq] = vA; buf[2 * pq + 1] = vB;
    }
    // carry == tile aggregate (identical on all lanes)

    // ---- publish aggregate ASAP ----
    if (lane == 0)
        __hip_atomic_store(&agg[tile], carry,
                           __ATOMIC_RELAXED, __HIP_MEMORY_SCOPE_AGENT);

    // ---- lookback: exclusive prefix over preceding tiles of this row ----
    float p = 1.0f;
    if (seg != 0) {
        if (lane == 0) {
            unsigned b = tile - 1;
            const unsigned first = tile - seg;      // row's tile 0
            for (;;) {
                float pr = __hip_atomic_load(&pref[b],
                    __ATOMIC_RELAXED, __HIP_MEMORY_SCOPE_AGENT);
                if (pr != 0.0f) { p *= pr; break; }  // inclusive prefix found
                float ag = __hip_atomic_load(&agg[b],
                    __ATOMIC_RELAXED, __HIP_MEMORY_SCOPE_AGENT);
                if (ag != 0.0f) {
                    p *= ag;
                    if (b == first) break;
                    --b;
                } else {
                    __builtin_amdgcn_s_sleep(1);     // predecessor not yet published
                }
            }
        }
        p = __shfl(p, 0);
    }

    // ---- publish inclusive prefix (successors within row need it) ----
    if (lane == 0 && seg != SEGS - 1)
        __hip_atomic_store(&pref[tile], p * carry,
                           __ATOMIC_RELAXED, __HIP_MEMORY_SCOPE_AGENT);

    // ---- scale and burst-store ----
    #pragma unroll
    for (int j = 0; j < TCH; ++j) {
        f32x4 o = buf[j];
        o[0] *= p; o[1] *= p; o[2] *= p; o[3] *= p;
        __builtin_nontemporal_store(o, reinterpret_cast<f32x4*>(po + j * CHUNK));
    }
}

// ---------------- fallback: R10 wave-per-row kernel ----------------
#define NPAIR (COLS / (2 * CHUNK))
#define PFP   2

__global__ __launch_bounds__(TPB) void cumprod_rows(const float* __restrict__ x,
                                                    float* __restrict__ out) {
    const int lane = threadIdx.x & 63;
    const int wid  = threadIdx.x >> 6;
    const int row  = blockIdx.x * WPB + wid;
    const size_t base = (size_t)row * (size_t)COLS + (size_t)lane * 4;
    const float* px = x + base;
    float*       po = out + base;

    f32x4 buf[PFP][2];
    #pragma unroll
    for (int j = 0; j < PFP; ++j) {
        buf[j][0] = __builtin_nontemporal_load(
            reinterpret_cast<const f32x4*>(px + (2 * j)     * CHUNK));
        buf[j][1] = __builtin_nontemporal_load(
            reinterpret_cast<const f32x4*>(px + (2 * j + 1) * CHUNK));
    }
    float carry = 1.0f;
    for (int p = 0; p < NPAIR; p += PFP) {
        #pragma unroll
        for (int j = 0; j < PFP; ++j) {
            f32x4 vA = buf[j][0], vB = buf[j][1];
            const int np = p + j + PFP;
            if (np < NPAIR) {
                buf[j][0] = __builtin_nontemporal_load(
                    reinterpret_cast<const f32x4*>(px + (2 * np)     * CHUNK));
                buf[j][1] = __builtin_nontemporal_load(
                    reinterpret_cast<const f32x4*>(px + (2 * np + 1) * CHUNK));
            }
            vA[1] *= vA[0]; vB[1] *= vB[0];
            vA[2] *= vA[1]; vB[2] *= vB[1];
            vA[3] *= vA[2]; vB[3] *= vB[2];
            float tA = wave_scan(vA[3]);
            float tB = wave_scan(vB[3]);
            float exA = excl(tA), exB = excl(tB);
            float TA = read63(tA), TB = read63(tB);
            const float mA = carry * exA;
            const float cA = carry * TA;
            const float mB = cA * exB;
            carry = cA * TB;
            f32x4 oA, oB;
            oA[0] = vA[0] * mA; oB[0] = vB[0] * mB;
            oA[1] = vA[1] * mA; oB[1] = vB[1] * mB;
            oA[2] = vA[2] * mA; oB[2] = vB[2] * mB;
            oA[3] = vA[3] * mA; oB[3] = vB[3] * mB;
            __builtin_nontemporal_store(oA,
                reinterpret_cast<f32x4*>(po + (2 * (p + j))     * CHUNK));
            __builtin_nontemporal_store(oB,
                reinterpret_cast<f32x4*>(po + (2 * (p + j) + 1) * CHUNK));
        }
    }
}

extern "C" void kernel_launch(void* const* d_in, const int* in_sizes, int n_in,
                              void* d_out, int out_size, void* d_ws, size_t ws_size,
                              hipStream_t stream) {
    const float* x = (const float*)d_in[0];
    float* out = (float*)d_out;
    const int rows   = out_size / COLS;          // 4096
    const int ntiles = rows * SEGS;              // 65536

    // ws layout: [0,4)=ticket counter, [64, 64+ntiles*4)=agg, then pref
    const size_t need = 64 + (size_t)ntiles * 4 * 2;
    if (ws_size >= need) {
        hipMemsetAsync(d_ws, 0, need, stream);   // zero flags+ticket EVERY launch
        unsigned* ctr = (unsigned*)d_ws;
        float* agg  = (float*)((char*)d_ws + 64);
        float* pref = agg + ntiles;
        cumprod_lookback<<<ntiles / WPB, TPB, 0, stream>>>(x, out, ctr, agg, pref);
    } else {
        cumprod_rows<<<rows / WPB, TPB, 0, stream>>>(x, out);
    }
}

// Round 12
// 255.392 us; speedup vs baseline: 1.0884x; 1.0884x over previous
//
#include <hip/hip_runtime.h>

// Cumulative product along last dim of (4096, 32768) fp32.
// SINGLE-PASS TILE SCAN WITH PARALLEL-WINDOW LOOKBACK (agg-only):
//   row -> 16 tiles x 2048 elems, ONE WAVE PER TILE (65536 waves).
//   Per wave: 8 nt loads (burst, ONE wait) -> pair-ILP DPP scan ->
//   publish tile aggregate -> PARALLEL lookback (lane l polls predecessor
//   l's agg; one vector load per round; shfl_xor product-reduce) ->
//   scale -> 8 nt stores -> wave ends (store acks block nothing).
// vs R11 (278us): no pref[] chain, no serial lane-0 walk — zero
// cross-tile dependency chain; lookback is one parallel poll round.
// Value-as-flag: aggregates strictly positive (inputs in [0.95,1.05]),
// 0.0 == unpublished; relaxed agent-scope atomics. Ticket preserves
// schedule order for progress. Flags in d_ws, memset every launch.

#define COLS   32768
#define CHUNK  256                 // 64 lanes x float4
#define TCH    8                   // chunks per tile
#define TILE   (TCH * CHUNK)       // 2048 elems
#define SEGS   (COLS / TILE)       // 16 tiles per row
#define TPB    256
#define WPB    (TPB / 64)          // 4 waves (tiles) per block

typedef float f32x4 __attribute__((ext_vector_type(4)));

#define ONE_BITS 0x3f800000        // 1.0f bits (multiplicative identity)

template <int CTRL, int RM, int BM>
__device__ __forceinline__ float mul_dpp(float x) {
    int s = __builtin_amdgcn_update_dpp(ONE_BITS, __float_as_int(x),
                                        CTRL, RM, BM, false);
    return x * __int_as_float(s);
}

__device__ __forceinline__ float wave_scan(float t) {
    t = mul_dpp<0x111, 0xf, 0xf>(t);   // row_shr:1
    t = mul_dpp<0x112, 0xf, 0xf>(t);   // row_shr:2
    t = mul_dpp<0x114, 0xf, 0xf>(t);   // row_shr:4
    t = mul_dpp<0x118, 0xf, 0xf>(t);   // row_shr:8
    t = mul_dpp<0x142, 0xa, 0xf>(t);   // row_bcast:15 -> rows 1,3
    t = mul_dpp<0x143, 0xc, 0xf>(t);   // row_bcast:31 -> rows 2,3
    return t;
}

__device__ __forceinline__ float excl(float t) {
    return __int_as_float(__builtin_amdgcn_update_dpp(
        ONE_BITS, __float_as_int(t), 0x138, 0xf, 0xf, false));
}

__device__ __forceinline__ float read63(float t) {
    return __int_as_float(__builtin_amdgcn_readlane(__float_as_int(t), 63));
}

__global__ __launch_bounds__(TPB) void cumprod_lookback(
    const float* __restrict__ x, float* __restrict__ out,
    unsigned* __restrict__ ticket_ctr, float* __restrict__ agg) {

    __shared__ unsigned tk_s;
    if (threadIdx.x == 0) tk_s = atomicAdd(ticket_ctr, 1u);
    __syncthreads();

    const int lane = threadIdx.x & 63;
    const int wid  = threadIdx.x >> 6;
    const unsigned tile = tk_s * WPB + wid;
    const int row = tile >> 4;               // SEGS = 16
    const int seg = tile & (SEGS - 1);

    const size_t base = (size_t)row * COLS + (size_t)seg * TILE + (size_t)lane * 4;
    const float* px = x + base;
    float*       po = out + base;

    // ---- burst-load the whole tile: 8 independent nt loads, ONE wait ----
    f32x4 buf[TCH];
    #pragma unroll
    for (int j = 0; j < TCH; ++j)
        buf[j] = __builtin_nontemporal_load(
            reinterpret_cast<const f32x4*>(px + j * CHUNK));

    // ---- local scan: 4 chunk-pairs, independent DPP chains per pair ----
    float carry = 1.0f;
    #pragma unroll
    for (int pq = 0; pq < TCH / 2; ++pq) {
        f32x4 vA = buf[2 * pq], vB = buf[2 * pq + 1];
        vA[1] *= vA[0]; vB[1] *= vB[0];
        vA[2] *= vA[1]; vB[2] *= vB[1];
        vA[3] *= vA[2]; vB[3] *= vB[2];
        float tA = wave_scan(vA[3]);
        float tB = wave_scan(vB[3]);
        float exA = excl(tA), exB = excl(tB);
        float TA = read63(tA), TB = read63(tB);
        const float mA = carry * exA;
        const float cA = carry * TA;
        const float mB = cA * exB;
        carry = cA * TB;
        vA[0] *= mA; vA[1] *= mA; vA[2] *= mA; vA[3] *= mA;
        vB[0] *= mB; vB[1] *= mB; vB[2] *= mB; vB[3] *= mB;
        buf[2 * pq] = vA; buf[2 * pq + 1] = vB;
    }
    // carry == tile aggregate (identical on all lanes)

    // ---- publish aggregate immediately (depends on nobody) ----
    if (lane == 0)
        __hip_atomic_store(&agg[tile], carry,
                           __ATOMIC_RELAXED, __HIP_MEMORY_SCOPE_AGENT);

    // ---- PARALLEL-WINDOW lookback: lane l polls predecessor l ----
    float p = 1.0f;
    if (seg != 0) {
        float v = 1.0f;
        if (lane < seg) {
            const float* a = &agg[tile - seg + lane];
            v = __hip_atomic_load(a, __ATOMIC_RELAXED,
                                  __HIP_MEMORY_SCOPE_AGENT);
            while (v == 0.0f) {                 // lanes mask off as they finish
                __builtin_amdgcn_s_sleep(2);
                v = __hip_atomic_load(a, __ATOMIC_RELAXED,
                                      __HIP_MEMORY_SCOPE_AGENT);
            }
        }
        // full-wave product reduce (lanes >= seg contribute 1.0)
        #pragma unroll
        for (int off = 32; off >= 1; off >>= 1) v *= __shfl_xor(v, off);
        p = v;
    }

    // ---- scale and burst-store; wave ends, store acks block nothing ----
    #pragma unroll
    for (int j = 0; j < TCH; ++j) {
        f32x4 o = buf[j];
        o[0] *= p; o[1] *= p; o[2] *= p; o[3] *= p;
        __builtin_nontemporal_store(o, reinterpret_cast<f32x4*>(po + j * CHUNK));
    }
}

// ---------------- fallback: R10 wave-per-row kernel ----------------
#define NPAIR (COLS / (2 * CHUNK))
#define PFP   2

__global__ __launch_bounds__(TPB) void cumprod_rows(const float* __restrict__ x,
                                                    float* __restrict__ out) {
    const int lane = threadIdx.x & 63;
    const int wid  = threadIdx.x >> 6;
    const int row  = blockIdx.x * WPB + wid;
    const size_t base = (size_t)row * (size_t)COLS + (size_t)lane * 4;
    const float* px = x + base;
    float*       po = out + base;

    f32x4 buf[PFP][2];
    #pragma unroll
    for (int j = 0; j < PFP; ++j) {
        buf[j][0] = __builtin_nontemporal_load(
            reinterpret_cast<const f32x4*>(px + (2 * j)     * CHUNK));
        buf[j][1] = __builtin_nontemporal_load(
            reinterpret_cast<const f32x4*>(px + (2 * j + 1) * CHUNK));
    }
    float carry = 1.0f;
    for (int p = 0; p < NPAIR; p += PFP) {
        #pragma unroll
        for (int j = 0; j < PFP; ++j) {
            f32x4 vA = buf[j][0], vB = buf[j][1];
            const int np = p + j + PFP;
            if (np < NPAIR) {
                buf[j][0] = __builtin_nontemporal_load(
                    reinterpret_cast<const f32x4*>(px + (2 * np)     * CHUNK));
                buf[j][1] = __builtin_nontemporal_load(
                    reinterpret_cast<const f32x4*>(px + (2 * np + 1) * CHUNK));
            }
            vA[1] *= vA[0]; vB[1] *= vB[0];
            vA[2] *= vA[1]; vB[2] *= vB[1];
            vA[3] *= vA[2]; vB[3] *= vB[2];
            float tA = wave_scan(vA[3]);
            float tB = wave_scan(vB[3]);
            float exA = excl(tA), exB = excl(tB);
            float TA = read63(tA), TB = read63(tB);
            const float mA = carry * exA;
            const float cA = carry * TA;
            const float mB = cA * exB;
            carry = cA * TB;
            f32x4 oA, oB;
            oA[0] = vA[0] * mA; oB[0] = vB[0] * mB;
            oA[1] = vA[1] * mA; oB[1] = vB[1] * mB;
            oA[2] = vA[2] * mA; oB[2] = vB[2] * mB;
            oA[3] = vA[3] * mA; oB[3] = vB[3] * mB;
            __builtin_nontemporal_store(oA,
                reinterpret_cast<f32x4*>(po + (2 * (p + j))     * CHUNK));
            __builtin_nontemporal_store(oB,
                reinterpret_cast<f32x4*>(po + (2 * (p + j) + 1) * CHUNK));
        }
    }
}

extern "C" void kernel_launch(void* const* d_in, const int* in_sizes, int n_in,
                              void* d_out, int out_size, void* d_ws, size_t ws_size,
                              hipStream_t stream) {
    const float* x = (const float*)d_in[0];
    float* out = (float*)d_out;
    const int rows   = out_size / COLS;          // 4096
    const int ntiles = rows * SEGS;              // 65536

    // ws layout: [0,4)=ticket counter, [64, 64+ntiles*4)=agg
    const size_t need = 64 + (size_t)ntiles * 4;
    if (ws_size >= need) {
        hipMemsetAsync(d_ws, 0, need, stream);   // zero ticket+aggs EVERY launch
        unsigned* ctr = (unsigned*)d_ws;
        float* agg = (float*)((char*)d_ws + 64);
        cumprod_lookback<<<ntiles / WPB, TPB, 0, stream>>>(x, out, ctr, agg);
    } else {
        cumprod_rows<<<rows / WPB, TPB, 0, stream>>>(x, out);
    }
}

// Round 13
// 190.707 us; speedup vs baseline: 1.4576x; 1.3392x over previous
//
#include <hip/hip_runtime.h>

// Cumulative product along last dim of (4096, 32768) fp32.
// ONE BLOCK (1024 thr = 16 waves) PER ROW; each wave owns a contiguous
// 2048-elem tile (8 x float4 per lane). Phases: 8-load nt burst ->
// pair-ILP DPP local scan -> one LDS round + __syncthreads ->
// 16-lane shfl_xor butterfly combine -> scale -> 8-store nt burst.
// __launch_bounds__(1024, 8) caps VGPR at 64 so TWO blocks co-reside
// per CU (32 waves/CU): one block's load burst overlaps the other's
// scan/store phase — the cross-phase overlap R2's 1-block/CU lacked.
// No global coordination (R11/R12's cross-XCD poll cost rejected).

#define COLS  32768
#define TPB   1024
#define NW    (TPB / 64)          // 16 waves per block
#define PERW  (COLS / NW)         // 2048 elems per wave tile
#define TCH   8                   // float4 chunks per lane (8*256=2048)
#define CHUNK 256                 // elems per chunk (64 lanes x 4)

typedef float f32x4 __attribute__((ext_vector_type(4)));

#define ONE_BITS 0x3f800000       // 1.0f bits (multiplicative identity)

template <int CTRL, int RM, int BM>
__device__ __forceinline__ float mul_dpp(float x) {
    int s = __builtin_amdgcn_update_dpp(ONE_BITS, __float_as_int(x),
                                        CTRL, RM, BM, false);
    return x * __int_as_float(s);
}

__device__ __forceinline__ float wave_scan(float t) {
    t = mul_dpp<0x111, 0xf, 0xf>(t);   // row_shr:1
    t = mul_dpp<0x112, 0xf, 0xf>(t);   // row_shr:2
    t = mul_dpp<0x114, 0xf, 0xf>(t);   // row_shr:4
    t = mul_dpp<0x118, 0xf, 0xf>(t);   // row_shr:8
    t = mul_dpp<0x142, 0xa, 0xf>(t);   // row_bcast:15 -> rows 1,3
    t = mul_dpp<0x143, 0xc, 0xf>(t);   // row_bcast:31 -> rows 2,3
    return t;
}

__device__ __forceinline__ float excl(float t) {
    return __int_as_float(__builtin_amdgcn_update_dpp(
        ONE_BITS, __float_as_int(t), 0x138, 0xf, 0xf, false));
}

__device__ __forceinline__ float read63(float t) {
    return __int_as_float(__builtin_amdgcn_readlane(__float_as_int(t), 63));
}

__global__ __launch_bounds__(TPB, 8) void cumprod_rows(
    const float* __restrict__ x, float* __restrict__ out) {

    const int lane = threadIdx.x & 63;
    const int wid  = threadIdx.x >> 6;          // 0..15

    const size_t base = (size_t)blockIdx.x * COLS
                      + (size_t)wid * PERW + (size_t)lane * 4;
    const float* px = x + base;
    float*       po = out + base;

    // ---- burst-load the wave tile: 8 independent nt loads ----
    f32x4 buf[TCH];
    #pragma unroll
    for (int j = 0; j < TCH; ++j)
        buf[j] = __builtin_nontemporal_load(
            reinterpret_cast<const f32x4*>(px + j * CHUNK));

    // ---- local scan: 4 chunk-pairs, independent DPP chains per pair ----
    float carry = 1.0f;
    #pragma unroll
    for (int pq = 0; pq < TCH / 2; ++pq) {
        f32x4 vA = buf[2 * pq], vB = buf[2 * pq + 1];
        vA[1] *= vA[0]; vB[1] *= vB[0];
        vA[2] *= vA[1]; vB[2] *= vB[1];
        vA[3] *= vA[2]; vB[3] *= vB[2];
        float tA = wave_scan(vA[3]);
        float tB = wave_scan(vB[3]);
        float exA = excl(tA), exB = excl(tB);
        float TA = read63(tA), TB = read63(tB);
        const float mA = carry * exA;
        const float cA = carry * TA;
        const float mB = cA * exB;
        carry = cA * TB;
        vA[0] *= mA; vA[1] *= mA; vA[2] *= mA; vA[3] *= mA;
        vB[0] *= mB; vB[1] *= mB; vB[2] *= mB; vB[3] *= mB;
        buf[2 * pq] = vA; buf[2 * pq + 1] = vB;
    }
    // carry == wave-tile aggregate (uniform across lanes)

    // ---- block combine: one LDS round + one barrier ----
    __shared__ float wt[NW];
    if (lane == 0) wt[wid] = carry;
    __syncthreads();

    // lanes 0..15 fetch one predecessor total each; butterfly product
    float v = 1.0f;
    if (lane < wid) v = wt[lane];               // conflict-free, banks 0..15
    v *= __shfl_xor(v, 1);
    v *= __shfl_xor(v, 2);
    v *= __shfl_xor(v, 4);
    v *= __shfl_xor(v, 8);                      // lanes 0..15 now hold product
    const float p = __shfl(v, 0);               // exclusive wave prefix

    // ---- scale and burst-store ----
    #pragma unroll
    for (int j = 0; j < TCH; ++j) {
        f32x4 o = buf[j];
        o[0] *= p; o[1] *= p; o[2] *= p; o[3] *= p;
        __builtin_nontemporal_store(o, reinterpret_cast<f32x4*>(po + j * CHUNK));
    }
}

extern "C" void kernel_launch(void* const* d_in, const int* in_sizes, int n_in,
                              void* d_out, int out_size, void* d_ws, size_t ws_size,
                              hipStream_t stream) {
    const float* x = (const float*)d_in[0];
    float* out = (float*)d_out;
    const int rows = out_size / COLS;           // 4096
    cumprod_rows<<<rows, TPB, 0, stream>>>(x, out);
}

// Round 14
// 189.047 us; speedup vs baseline: 1.4704x; 1.0088x over previous
//
#include <hip/hip_runtime.h>

// Cumulative product along last dim of (4096, 32768) fp32.
// ONE BLOCK (1024 thr = 16 waves) PER ROW; each wave owns a contiguous
// 2048-elem tile (8 x float4 per lane). __launch_bounds__(1024, 8) caps
// VGPR at 64 so TWO blocks co-reside per CU (R13: 190.7us).
// vs R13: the full-block __syncthreads rendezvous after the local scan is
// replaced by in-LDS PUBLISH-AND-POLL (value-as-flag, workgroup scope).
// Only a cheap pre-load barrier remains (LDS slot zero-init; all waves
// arrive together). Wave w's store phase now starts as soon as waves
// 0..w-1 published — stores stagger and overlap stragglers' loads,
// removing the convoy effect (max-of-16 load-tail latency per block).

#define COLS  32768
#define TPB   1024
#define NW    (TPB / 64)          // 16 waves per block
#define PERW  (COLS / NW)         // 2048 elems per wave tile
#define TCH   8                   // float4 chunks per lane
#define CHUNK 256                 // elems per chunk (64 lanes x 4)

typedef float f32x4 __attribute__((ext_vector_type(4)));

#define ONE_BITS 0x3f800000       // 1.0f bits (multiplicative identity)

template <int CTRL, int RM, int BM>
__device__ __forceinline__ float mul_dpp(float x) {
    int s = __builtin_amdgcn_update_dpp(ONE_BITS, __float_as_int(x),
                                        CTRL, RM, BM, false);
    return x * __int_as_float(s);
}

__device__ __forceinline__ float wave_scan(float t) {
    t = mul_dpp<0x111, 0xf, 0xf>(t);   // row_shr:1
    t = mul_dpp<0x112, 0xf, 0xf>(t);   // row_shr:2
    t = mul_dpp<0x114, 0xf, 0xf>(t);   // row_shr:4
    t = mul_dpp<0x118, 0xf, 0xf>(t);   // row_shr:8
    t = mul_dpp<0x142, 0xa, 0xf>(t);   // row_bcast:15 -> rows 1,3
    t = mul_dpp<0x143, 0xc, 0xf>(t);   // row_bcast:31 -> rows 2,3
    return t;
}

__device__ __forceinline__ float excl(float t) {
    return __int_as_float(__builtin_amdgcn_update_dpp(
        ONE_BITS, __float_as_int(t), 0x138, 0xf, 0xf, false));
}

__device__ __forceinline__ float read63(float t) {
    return __int_as_float(__builtin_amdgcn_readlane(__float_as_int(t), 63));
}

__global__ __launch_bounds__(TPB, 8) void cumprod_rows(
    const float* __restrict__ x, float* __restrict__ out) {

    const int lane = threadIdx.x & 63;
    const int wid  = threadIdx.x >> 6;          // 0..15

    __shared__ float wt[NW];
    if (threadIdx.x < NW) wt[threadIdx.x] = 0.0f;   // 0 == unpublished
    __syncthreads();   // cheap: before loads, all waves arrive together

    const size_t base = (size_t)blockIdx.x * COLS
                      + (size_t)wid * PERW + (size_t)lane * 4;
    const float* px = x + base;
    float*       po = out + base;

    // ---- burst-load the wave tile: 8 independent nt loads ----
    f32x4 buf[TCH];
    #pragma unroll
    for (int j = 0; j < TCH; ++j)
        buf[j] = __builtin_nontemporal_load(
            reinterpret_cast<const f32x4*>(px + j * CHUNK));

    // ---- local scan: 4 chunk-pairs, independent DPP chains per pair ----
    float carry = 1.0f;
    #pragma unroll
    for (int pq = 0; pq < TCH / 2; ++pq) {
        f32x4 vA = buf[2 * pq], vB = buf[2 * pq + 1];
        vA[1] *= vA[0]; vB[1] *= vB[0];
        vA[2] *= vA[1]; vB[2] *= vB[1];
        vA[3] *= vA[2]; vB[3] *= vB[2];
        float tA = wave_scan(vA[3]);
        float tB = wave_scan(vB[3]);
        float exA = excl(tA), exB = excl(tB);
        float TA = read63(tA), TB = read63(tB);
        const float mA = carry * exA;
        const float cA = carry * TA;
        const float mB = cA * exB;
        carry = cA * TB;
        vA[0] *= mA; vA[1] *= mA; vA[2] *= mA; vA[3] *= mA;
        vB[0] *= mB; vB[1] *= mB; vB[2] *= mB; vB[3] *= mB;
        buf[2 * pq] = vA; buf[2 * pq + 1] = vB;
    }
    // carry == wave-tile aggregate (uniform across lanes, strictly > 0)

    // ---- publish own aggregate (release, workgroup scope) ----
    if (lane == 0)
        __hip_atomic_store(&wt[wid], carry,
                           __ATOMIC_RELEASE, __HIP_MEMORY_SCOPE_WORKGROUP);

    // ---- poll predecessors: lane l < wid polls wt[l] ----
    float v = 1.0f;
    if (lane < wid) {
        v = __hip_atomic_load(&wt[lane],
                              __ATOMIC_ACQUIRE, __HIP_MEMORY_SCOPE_WORKGROUP);
        while (v == 0.0f) {                     // lanes mask off as slots fill
            __builtin_amdgcn_s_sleep(1);
            v = __hip_atomic_load(&wt[lane],
                                  __ATOMIC_ACQUIRE, __HIP_MEMORY_SCOPE_WORKGROUP);
        }
    }
    // butterfly product over the 16-lane group (lanes >= wid contribute 1.0)
    v *= __shfl_xor(v, 1);
    v *= __shfl_xor(v, 2);
    v *= __shfl_xor(v, 4);
    v *= __shfl_xor(v, 8);
    const float p = __shfl(v, 0);               // exclusive wave prefix

    // ---- scale and burst-store; wave exits when done ----
    #pragma unroll
    for (int j = 0; j < TCH; ++j) {
        f32x4 o = buf[j];
        o[0] *= p; o[1] *= p; o[2] *= p; o[3] *= p;
        __builtin_nontemporal_store(o, reinterpret_cast<f32x4*>(po + j * CHUNK));
    }
}

extern "C" void kernel_launch(void* const* d_in, const int* in_sizes, int n_in,
                              void* d_out, int out_size, void* d_ws, size_t ws_size,
                              hipStream_t stream) {
    const float* x = (const float*)d_in[0];
    float* out = (float*)d_out;
    const int rows = out_size / COLS;           // 4096
    cumprod_rows<<<rows, TPB, 0, stream>>>(x, out);
}